// Round 1
// baseline (257.982 us; speedup 1.0000x reference)
//
#include <hip/hip_runtime.h>

#define NQ      4
#define DIMQ    16
#define D_MODEL 1024
#define TPB     64      // tokens per block
#define CHUNK   128     // d-elements per LDS chunk
#define NCHUNK  8       // 1024 / 128
#define LROW    132     // padded LDS row (floats): keeps b128 reads conflict-free, 528B row = 16B-aligned
#define PI_F    3.14159265358979323846f

__global__ __launch_bounds__(256, 2)
void qffn_kernel(const float* __restrict__ x,
                 const float* __restrict__ Wi,
                 const float* __restrict__ bi,
                 const float* __restrict__ Wo,
                 const float* __restrict__ bo,
                 const float* __restrict__ fp,
                 float* __restrict__ out,
                 int n_tokens)
{
    __shared__ float s_x[TPB * LROW];       // 33.8 KB staged x chunk (64 tokens x 128 d, padded)
    __shared__ float s_wi[D_MODEL * 4];     // 16 KB Wi
    __shared__ float s_pq[4 * TPB * 4];     // 4 KB partial dot products
    __shared__ float s_q[TPB * 4];          // 1 KB quantum outputs per token

    const int tid  = threadIdx.x;
    const int lane = tid & 63;              // token within tile (dot/quantum phases)
    const int w    = tid >> 6;              // wave id = d-quarter
    const int tile = blockIdx.x * TPB;

    // ---- wave-uniform small params ----
    float pc[NQ], ps[NQ];
    #pragma unroll
    for (int q = 0; q < NQ; ++q) {
        float h = 0.5f * fp[q];
        pc[q] = __cosf(h);
        ps[q] = __sinf(h);
    }
    const float bi0 = bi[0], bi1 = bi[1], bi2 = bi[2], bi3 = bi[3];

    // ---- per-thread output-phase weights (4 fixed columns) ----
    const float4* Wo4 = (const float4*)Wo;
    const float4 wo0 = Wo4[0 * 256 + tid];
    const float4 wo1 = Wo4[1 * 256 + tid];
    const float4 wo2 = Wo4[2 * 256 + tid];
    const float4 wo3 = Wo4[3 * 256 + tid];
    const float4 bo4 = ((const float4*)bo)[tid];

    // ---- stage Wi into LDS (read later at wave-uniform addresses -> broadcast) ----
    {
        const float4* Wi4 = (const float4*)Wi;
        float4* s_wi4 = (float4*)s_wi;
        #pragma unroll
        for (int k = 0; k < 4; ++k) s_wi4[tid + k * 256] = Wi4[tid + k * 256];
    }

    // ---- prefetch chunk 0 into registers ----
    const float4* x4 = (const float4*)x;
    float4 xr[8];
    #pragma unroll
    for (int i = 0; i < 8; ++i) {
        int flat = tid + i * 256;
        int row = flat >> 5, col4 = flat & 31;
        int grow = tile + row; if (grow > n_tokens - 1) grow = n_tokens - 1;
        xr[i] = x4[grow * 256 + col4];
    }

    float p0 = 0.f, p1 = 0.f, p2 = 0.f, p3 = 0.f;

    for (int c = 0; c < NCHUNK; ++c) {
        // write current chunk regs -> LDS
        #pragma unroll
        for (int i = 0; i < 8; ++i) {
            int flat = tid + i * 256;
            int row = flat >> 5, col4 = flat & 31;
            *(float4*)&s_x[row * LROW + col4 * 4] = xr[i];
        }
        __syncthreads();
        // prefetch next chunk (stays in flight under the compute below)
        if (c + 1 < NCHUNK) {
            #pragma unroll
            for (int i = 0; i < 8; ++i) {
                int flat = tid + i * 256;
                int row = flat >> 5, col4 = flat & 31;
                int grow = tile + row; if (grow > n_tokens - 1) grow = n_tokens - 1;
                xr[i] = x4[grow * 256 + (c + 1) * 32 + col4];
            }
        }
        // dot partials: thread = (token=lane, quarter=w), 32 d's of this chunk
        const float*  xrow = &s_x[lane * LROW + w * 32];
        const float4* wv4  = (const float4*)&s_wi[(c * CHUNK + w * 32) * 4];
        #pragma unroll
        for (int j4 = 0; j4 < 8; ++j4) {
            float4 xv = *(const float4*)(xrow + j4 * 4);
            float4 wa = wv4[j4 * 4 + 0];
            float4 wb = wv4[j4 * 4 + 1];
            float4 wc = wv4[j4 * 4 + 2];
            float4 wd = wv4[j4 * 4 + 3];
            p0 = fmaf(xv.x, wa.x, p0); p1 = fmaf(xv.x, wa.y, p1); p2 = fmaf(xv.x, wa.z, p2); p3 = fmaf(xv.x, wa.w, p3);
            p0 = fmaf(xv.y, wb.x, p0); p1 = fmaf(xv.y, wb.y, p1); p2 = fmaf(xv.y, wb.z, p2); p3 = fmaf(xv.y, wb.w, p3);
            p0 = fmaf(xv.z, wc.x, p0); p1 = fmaf(xv.z, wc.y, p1); p2 = fmaf(xv.z, wc.z, p2); p3 = fmaf(xv.z, wc.w, p3);
            p0 = fmaf(xv.w, wd.x, p0); p1 = fmaf(xv.w, wd.y, p1); p2 = fmaf(xv.w, wd.z, p2); p3 = fmaf(xv.w, wd.w, p3);
        }
        __syncthreads();
    }

    // ---- reduce the 4 quarters per token ----
    *(float4*)&s_pq[tid * 4] = make_float4(p0, p1, p2, p3);
    __syncthreads();

    float4 a0 = *(const float4*)&s_pq[(0 * 64 + lane) * 4];
    float4 a1 = *(const float4*)&s_pq[(1 * 64 + lane) * 4];
    float4 a2 = *(const float4*)&s_pq[(2 * 64 + lane) * 4];
    float4 a3 = *(const float4*)&s_pq[(3 * 64 + lane) * 4];
    float xp0 = a0.x + a1.x + a2.x + a3.x + bi0;
    float xp1 = a0.y + a1.y + a2.y + a3.y + bi1;
    float xp2 = a0.z + a1.z + a2.z + a3.z + bi2;
    float xp3 = a0.w + a1.w + a2.w + a3.w + bi3;

    // ---- angles ----
    float mn = fminf(fminf(xp0, xp1), fminf(xp2, xp3));
    float mx = fmaxf(fmaxf(xp0, xp1), fmaxf(xp2, xp3));
    float inv = PI_F / (mx - mn + 1e-8f);
    float ang[NQ];
    ang[0] = (xp0 - mn) * inv;
    ang[1] = (xp1 - mn) * inv;
    ang[2] = (xp2 - mn) * inv;
    ang[3] = (xp3 - mn) * inv;

    // ---- 4-qubit statevector sim, one token per lane, all in registers ----
    float sr[DIMQ], si[DIMQ];
    #pragma unroll
    for (int k = 0; k < DIMQ; ++k) { sr[k] = (k == 0) ? 1.0f : 0.0f; si[k] = 0.0f; }

    // data RX gates
    #pragma unroll
    for (int q = 0; q < NQ; ++q) {
        const int bit = 8 >> q;
        float h = 0.5f * ang[q];
        float cth = __cosf(h), sth = __sinf(h);
        #pragma unroll
        for (int k = 0; k < DIMQ; ++k) {
            if (!(k & bit)) {
                const int k1 = k | bit;
                float a0r = sr[k],  a0i = si[k];
                float a1r = sr[k1], a1i = si[k1];
                sr[k]  = fmaf(cth, a0r,  sth * a1i);
                si[k]  = fmaf(cth, a0i, -sth * a1r);
                sr[k1] = fmaf(cth, a1r,  sth * a0i);
                si[k1] = fmaf(cth, a1i, -sth * a0r);
            }
        }
    }
    // param RX + CNOT ring
    #pragma unroll
    for (int q = 0; q < NQ; ++q) {
        const int bit = 8 >> q;
        float cth = pc[q], sth = ps[q];
        #pragma unroll
        for (int k = 0; k < DIMQ; ++k) {
            if (!(k & bit)) {
                const int k1 = k | bit;
                float a0r = sr[k],  a0i = si[k];
                float a1r = sr[k1], a1i = si[k1];
                sr[k]  = fmaf(cth, a0r,  sth * a1i);
                si[k]  = fmaf(cth, a0i, -sth * a1r);
                sr[k1] = fmaf(cth, a1r,  sth * a0i);
                si[k1] = fmaf(cth, a1i, -sth * a0r);
            }
        }
        const int cbit = 8 >> q;
        const int tbit = 8 >> ((q + 1) & 3);
        #pragma unroll
        for (int k = 0; k < DIMQ; ++k) {
            if ((k & cbit) && !(k & tbit)) {
                const int k1 = k | tbit;
                float t;
                t = sr[k]; sr[k] = sr[k1]; sr[k1] = t;
                t = si[k]; si[k] = si[k1]; si[k1] = t;
            }
        }
    }

    // ---- probs -> Z expectations ----
    float pr[DIMQ];
    #pragma unroll
    for (int k = 0; k < DIMQ; ++k) pr[k] = fmaf(sr[k], sr[k], si[k] * si[k]);

    float qv0 = 0.f, qv1 = 0.f, qv2 = 0.f, qv3 = 0.f;
    #pragma unroll
    for (int k = 0; k < DIMQ; ++k) {
        qv0 += (k & 8) ? -pr[k] : pr[k];
        qv1 += (k & 4) ? -pr[k] : pr[k];
        qv2 += (k & 2) ? -pr[k] : pr[k];
        qv3 += (k & 1) ? -pr[k] : pr[k];
    }

    if (tid < 64) *(float4*)&s_q[lane * 4] = make_float4(qv0, qv1, qv2, qv3);
    __syncthreads();

    // ---- output: thread owns columns [tid*4, tid*4+3], loops over 64 rows ----
    float4* out4 = (float4*)out;
    #pragma unroll 4
    for (int i = 0; i < TPB; ++i) {
        int grow = tile + i;
        if (grow < n_tokens) {
            float4 qq = *(const float4*)&s_q[i * 4];
            float4 v;
            v.x = fmaf(qq.x, wo0.x, fmaf(qq.y, wo1.x, fmaf(qq.z, wo2.x, fmaf(qq.w, wo3.x, bo4.x))));
            v.y = fmaf(qq.x, wo0.y, fmaf(qq.y, wo1.y, fmaf(qq.z, wo2.y, fmaf(qq.w, wo3.y, bo4.y))));
            v.z = fmaf(qq.x, wo0.z, fmaf(qq.y, wo1.z, fmaf(qq.z, wo2.z, fmaf(qq.w, wo3.z, bo4.z))));
            v.w = fmaf(qq.x, wo0.w, fmaf(qq.y, wo1.w, fmaf(qq.z, wo2.w, fmaf(qq.w, wo3.w, bo4.w))));
            out4[grow * 256 + tid] = v;
        }
    }
}

extern "C" void kernel_launch(void* const* d_in, const int* in_sizes, int n_in,
                              void* d_out, int out_size, void* d_ws, size_t ws_size,
                              hipStream_t stream)
{
    (void)d_ws; (void)ws_size; (void)n_in; (void)out_size;
    const float* x  = (const float*)d_in[0];
    const float* Wi = (const float*)d_in[1];
    const float* bi = (const float*)d_in[2];
    const float* Wo = (const float*)d_in[3];
    const float* bo = (const float*)d_in[4];
    const float* fp = (const float*)d_in[5];
    float* out = (float*)d_out;

    int n_tokens = in_sizes[0] / D_MODEL;
    int grid = (n_tokens + TPB - 1) / TPB;
    qffn_kernel<<<grid, 256, 0, stream>>>(x, Wi, bi, Wo, bo, fp, out, n_tokens);
}

// Round 4
// 242.501 us; speedup vs baseline: 1.0638x; 1.0638x over previous
//
#include <hip/hip_runtime.h>

#define NQ      4
#define DIMQ    16
#define D_MODEL 1024
#define TPB     64      // tokens per block
#define PI_F    3.14159265358979323846f

__global__ __launch_bounds__(256, 4)
void qffn_kernel(const float* __restrict__ x,
                 const float* __restrict__ Wi,
                 const float* __restrict__ bi,
                 const float* __restrict__ Wo,
                 const float* __restrict__ bo,
                 const float* __restrict__ fp,
                 float* __restrict__ out,
                 int n_tokens)
{
    __shared__ float s_xp[TPB * 4];   // per-token pre-activation (after bi)
    __shared__ float s_q[TPB * 4];    // per-token quantum outputs

    const int tid  = threadIdx.x;
    const int lane = tid & 63;
    const int w    = tid >> 6;        // wave id: owns tokens [w*16, w*16+16)
    const int tile = blockIdx.x * TPB;

    const float4* x4  = (const float4*)x;
    const float4* Wi4 = (const float4*)Wi;

    // ---- Wi slice for this lane, in registers: wi[c][e] = Wi row 4*(c*64+lane)+e ----
    float4 wi[4][4];
    #pragma unroll
    for (int c = 0; c < 4; ++c) {
        #pragma unroll
        for (int e = 0; e < 4; ++e)
            wi[c][e] = Wi4[(c * 64 + lane) * 4 + e];
    }
    const float bi0 = bi[0], bi1 = bi[1], bi2 = bi[2], bi3 = bi[3];

    // ---- dot phase: wave w handles its 16 tokens, butterfly-reduced ----
    float k0 = 0.f, k1 = 0.f, k2 = 0.f, k3 = 0.f;

    #define DOT4(xe, wv) \
        p0 = fmaf(xe, wv.x, p0); p1 = fmaf(xe, wv.y, p1); \
        p2 = fmaf(xe, wv.z, p2); p3 = fmaf(xe, wv.w, p3);

    #pragma unroll 2
    for (int t = 0; t < 16; ++t) {
        int tok = tile + w * 16 + t;
        if (tok > n_tokens - 1) tok = n_tokens - 1;
        const size_t base = (size_t)tok * 256;
        float4 xv0 = x4[base + 0 * 64 + lane];
        float4 xv1 = x4[base + 1 * 64 + lane];
        float4 xv2 = x4[base + 2 * 64 + lane];
        float4 xv3 = x4[base + 3 * 64 + lane];

        float p0 = 0.f, p1 = 0.f, p2 = 0.f, p3 = 0.f;
        DOT4(xv0.x, wi[0][0]) DOT4(xv0.y, wi[0][1]) DOT4(xv0.z, wi[0][2]) DOT4(xv0.w, wi[0][3])
        DOT4(xv1.x, wi[1][0]) DOT4(xv1.y, wi[1][1]) DOT4(xv1.z, wi[1][2]) DOT4(xv1.w, wi[1][3])
        DOT4(xv2.x, wi[2][0]) DOT4(xv2.y, wi[2][1]) DOT4(xv2.z, wi[2][2]) DOT4(xv2.w, wi[2][3])
        DOT4(xv3.x, wi[3][0]) DOT4(xv3.y, wi[3][1]) DOT4(xv3.z, wi[3][2]) DOT4(xv3.w, wi[3][3])

        // 6-stage butterfly: every lane ends with the full sums
        #pragma unroll
        for (int m = 1; m < 64; m <<= 1) {
            p0 += __shfl_xor(p0, m, 64);
            p1 += __shfl_xor(p1, m, 64);
            p2 += __shfl_xor(p2, m, 64);
            p3 += __shfl_xor(p3, m, 64);
        }
        if (lane == t) { k0 = p0; k1 = p1; k2 = p2; k3 = p3; }
    }

    if (lane < 16) {
        *(float4*)&s_xp[(w * 16 + lane) * 4] =
            make_float4(k0 + bi0, k1 + bi1, k2 + bi2, k3 + bi3);
    }

    // ---- output-phase weights: issue loads before the barrier (latency hides) ----
    const float4* Wo4 = (const float4*)Wo;
    const float4 wo0 = Wo4[0 * 256 + tid];
    const float4 wo1 = Wo4[1 * 256 + tid];
    const float4 wo2 = Wo4[2 * 256 + tid];
    const float4 wo3 = Wo4[3 * 256 + tid];
    const float4 bo4 = ((const float4*)bo)[tid];

    __syncthreads();

    // ---- quantum sim: wave 0 only, one token per lane, all in registers ----
    if (tid < 64) {
        float4 xpv = *(const float4*)&s_xp[tid * 4];
        float xp0 = xpv.x, xp1 = xpv.y, xp2 = xpv.z, xp3 = xpv.w;

        float pc[NQ], ps[NQ];
        #pragma unroll
        for (int q = 0; q < NQ; ++q) {
            float h = 0.5f * fp[q];
            pc[q] = __cosf(h);
            ps[q] = __sinf(h);
        }

        float mn = fminf(fminf(xp0, xp1), fminf(xp2, xp3));
        float mx = fmaxf(fmaxf(xp0, xp1), fmaxf(xp2, xp3));
        float inv = PI_F / (mx - mn + 1e-8f);
        float ang[NQ];
        ang[0] = (xp0 - mn) * inv;
        ang[1] = (xp1 - mn) * inv;
        ang[2] = (xp2 - mn) * inv;
        ang[3] = (xp3 - mn) * inv;

        float sr[DIMQ], si[DIMQ];
        #pragma unroll
        for (int k = 0; k < DIMQ; ++k) { sr[k] = (k == 0) ? 1.0f : 0.0f; si[k] = 0.0f; }

        #pragma unroll
        for (int q = 0; q < NQ; ++q) {
            const int bit = 8 >> q;
            float h = 0.5f * ang[q];
            float cth = __cosf(h), sth = __sinf(h);
            #pragma unroll
            for (int k = 0; k < DIMQ; ++k) {
                if (!(k & bit)) {
                    const int k1 = k | bit;
                    float a0r = sr[k],  a0i = si[k];
                    float a1r = sr[k1], a1i = si[k1];
                    sr[k]  = fmaf(cth, a0r,  sth * a1i);
                    si[k]  = fmaf(cth, a0i, -sth * a1r);
                    sr[k1] = fmaf(cth, a1r,  sth * a0i);
                    si[k1] = fmaf(cth, a1i, -sth * a0r);
                }
            }
        }
        #pragma unroll
        for (int q = 0; q < NQ; ++q) {
            const int bit = 8 >> q;
            float cth = pc[q], sth = ps[q];
            #pragma unroll
            for (int k = 0; k < DIMQ; ++k) {
                if (!(k & bit)) {
                    const int k1 = k | bit;
                    float a0r = sr[k],  a0i = si[k];
                    float a1r = sr[k1], a1i = si[k1];
                    sr[k]  = fmaf(cth, a0r,  sth * a1i);
                    si[k]  = fmaf(cth, a0i, -sth * a1r);
                    sr[k1] = fmaf(cth, a1r,  sth * a0i);
                    si[k1] = fmaf(cth, a1i, -sth * a0r);
                }
            }
            const int cbit = 8 >> q;
            const int tbit = 8 >> ((q + 1) & 3);
            #pragma unroll
            for (int k = 0; k < DIMQ; ++k) {
                if ((k & cbit) && !(k & tbit)) {
                    const int k1 = k | tbit;
                    float t;
                    t = sr[k]; sr[k] = sr[k1]; sr[k1] = t;
                    t = si[k]; si[k] = si[k1]; si[k1] = t;
                }
            }
        }

        float pr[DIMQ];
        #pragma unroll
        for (int k = 0; k < DIMQ; ++k) pr[k] = fmaf(sr[k], sr[k], si[k] * si[k]);

        float qv0 = 0.f, qv1 = 0.f, qv2 = 0.f, qv3 = 0.f;
        #pragma unroll
        for (int k = 0; k < DIMQ; ++k) {
            qv0 += (k & 8) ? -pr[k] : pr[k];
            qv1 += (k & 4) ? -pr[k] : pr[k];
            qv2 += (k & 2) ? -pr[k] : pr[k];
            qv3 += (k & 1) ? -pr[k] : pr[k];
        }
        *(float4*)&s_q[tid * 4] = make_float4(qv0, qv1, qv2, qv3);
    }

    __syncthreads();

    // ---- output: thread owns 4 fixed columns, loops over 64 rows ----
    float4* out4 = (float4*)out;
    #pragma unroll 8
    for (int i = 0; i < TPB; ++i) {
        int grow = tile + i;
        if (grow < n_tokens) {
            float4 qq = *(const float4*)&s_q[i * 4];
            float4 v;
            v.x = fmaf(qq.x, wo0.x, fmaf(qq.y, wo1.x, fmaf(qq.z, wo2.x, fmaf(qq.w, wo3.x, bo4.x))));
            v.y = fmaf(qq.x, wo0.y, fmaf(qq.y, wo1.y, fmaf(qq.z, wo2.y, fmaf(qq.w, wo3.y, bo4.y))));
            v.z = fmaf(qq.x, wo0.z, fmaf(qq.y, wo1.z, fmaf(qq.z, wo2.z, fmaf(qq.w, wo3.z, bo4.z))));
            v.w = fmaf(qq.x, wo0.w, fmaf(qq.y, wo1.w, fmaf(qq.z, wo2.w, fmaf(qq.w, wo3.w, bo4.w))));
            out4[(size_t)grow * 256 + tid] = v;
        }
    }
}

extern "C" void kernel_launch(void* const* d_in, const int* in_sizes, int n_in,
                              void* d_out, int out_size, void* d_ws, size_t ws_size,
                              hipStream_t stream)
{
    (void)d_ws; (void)ws_size; (void)n_in; (void)out_size;
    const float* x  = (const float*)d_in[0];
    const float* Wi = (const float*)d_in[1];
    const float* bi = (const float*)d_in[2];
    const float* Wo = (const float*)d_in[3];
    const float* bo = (const float*)d_in[4];
    const float* fp = (const float*)d_in[5];
    float* out = (float*)d_out;

    int n_tokens = in_sizes[0] / D_MODEL;
    int grid = (n_tokens + TPB - 1) / TPB;
    qffn_kernel<<<grid, 256, 0, stream>>>(x, Wi, bi, Wo, bo, fp, out, n_tokens);
}

// Round 7
// 242.427 us; speedup vs baseline: 1.0642x; 1.0003x over previous
//
#include <hip/hip_runtime.h>

#define NQ      4
#define DIMQ    16
#define D_MODEL 1024
#define TPB     64      // tokens per block == 64 lanes
#define PI_F    3.14159265358979323846f

__global__ __launch_bounds__(256, 4)
void qffn_kernel(const float* __restrict__ x,
                 const float* __restrict__ Wi,
                 const float* __restrict__ bi,
                 const float* __restrict__ Wo,
                 const float* __restrict__ bo,
                 const float* __restrict__ fp,
                 float* __restrict__ out,
                 int n_tokens)
{
    __shared__ float s_part[256 * 4];  // 4 KB: per-(wave,token) quarter partials
    __shared__ float s_q[TPB * 4];     // 1 KB: per-token quantum outputs

    const int tid  = threadIdx.x;
    const int lane = tid & 63;
    const int w    = tid >> 6;
    const int tile = blockIdx.x * TPB;

    const float4* x4  = (const float4*)x;
    const float4* Wi4 = (const float4*)Wi;

    // ---- Wi slice: thread owns elements 4*tid..4*tid+3 -> 4 rows of Wi = 16 VGPRs ----
    const float4 wiA = Wi4[tid * 4 + 0];
    const float4 wiB = Wi4[tid * 4 + 1];
    const float4 wiC = Wi4[tid * 4 + 2];
    const float4 wiD = Wi4[tid * 4 + 3];

    // ---- output-phase weights (loaded once, used at the end) ----
    const float4* Wo4 = (const float4*)Wo;
    const float4 wo0 = Wo4[0 * 256 + tid];
    const float4 wo1 = Wo4[1 * 256 + tid];
    const float4 wo2 = Wo4[2 * 256 + tid];
    const float4 wo3 = Wo4[3 * 256 + tid];
    const float4 bo4 = ((const float4*)bo)[tid];

    // ---- token loop: whole block cooperates on each token ----
    // per token: one coalesced 4KB block load; butterfly gives quarter-sum
    // in every lane of each wave; lane t keeps token t's quarter-partial.
    float4 k = make_float4(0.f, 0.f, 0.f, 0.f);

    const int last = n_tokens - 1;
    #pragma unroll 8
    for (int t = 0; t < TPB; ++t) {
        int tok = tile + t; if (tok > last) tok = last;
        float4 xv = x4[(size_t)tok * 256 + tid];

        float p0, p1, p2, p3;
        p0 = xv.x * wiA.x; p1 = xv.x * wiA.y; p2 = xv.x * wiA.z; p3 = xv.x * wiA.w;
        p0 = fmaf(xv.y, wiB.x, p0); p1 = fmaf(xv.y, wiB.y, p1); p2 = fmaf(xv.y, wiB.z, p2); p3 = fmaf(xv.y, wiB.w, p3);
        p0 = fmaf(xv.z, wiC.x, p0); p1 = fmaf(xv.z, wiC.y, p1); p2 = fmaf(xv.z, wiC.z, p2); p3 = fmaf(xv.z, wiC.w, p3);
        p0 = fmaf(xv.w, wiD.x, p0); p1 = fmaf(xv.w, wiD.y, p1); p2 = fmaf(xv.w, wiD.z, p2); p3 = fmaf(xv.w, wiD.w, p3);

        #pragma unroll
        for (int m = 1; m < 64; m <<= 1) {
            p0 += __shfl_xor(p0, m, 64);
            p1 += __shfl_xor(p1, m, 64);
            p2 += __shfl_xor(p2, m, 64);
            p3 += __shfl_xor(p3, m, 64);
        }
        if (lane == t) { k.x = p0; k.y = p1; k.z = p2; k.w = p3; }
    }

    // each lane's k is token `lane`'s quarter-partial for wave w
    *(float4*)&s_part[tid * 4] = k;
    __syncthreads();

    // ---- quantum sim: wave 0, one token per lane, all in registers ----
    if (tid < 64) {
        float4 a0 = *(const float4*)&s_part[(0 * 64 + tid) * 4];
        float4 a1 = *(const float4*)&s_part[(1 * 64 + tid) * 4];
        float4 a2 = *(const float4*)&s_part[(2 * 64 + tid) * 4];
        float4 a3 = *(const float4*)&s_part[(3 * 64 + tid) * 4];
        float xp0 = a0.x + a1.x + a2.x + a3.x + bi[0];
        float xp1 = a0.y + a1.y + a2.y + a3.y + bi[1];
        float xp2 = a0.z + a1.z + a2.z + a3.z + bi[2];
        float xp3 = a0.w + a1.w + a2.w + a3.w + bi[3];

        float pc[NQ], ps[NQ];
        #pragma unroll
        for (int q = 0; q < NQ; ++q) {
            float h = 0.5f * fp[q];
            pc[q] = __cosf(h);
            ps[q] = __sinf(h);
        }

        float mn = fminf(fminf(xp0, xp1), fminf(xp2, xp3));
        float mx = fmaxf(fmaxf(xp0, xp1), fmaxf(xp2, xp3));
        float inv = PI_F / (mx - mn + 1e-8f);
        float ang[NQ];
        ang[0] = (xp0 - mn) * inv;
        ang[1] = (xp1 - mn) * inv;
        ang[2] = (xp2 - mn) * inv;
        ang[3] = (xp3 - mn) * inv;

        float sr[DIMQ], si[DIMQ];
        #pragma unroll
        for (int kk = 0; kk < DIMQ; ++kk) { sr[kk] = (kk == 0) ? 1.0f : 0.0f; si[kk] = 0.0f; }

        #pragma unroll
        for (int q = 0; q < NQ; ++q) {
            const int bit = 8 >> q;
            float h = 0.5f * ang[q];
            float cth = __cosf(h), sth = __sinf(h);
            #pragma unroll
            for (int kk = 0; kk < DIMQ; ++kk) {
                if (!(kk & bit)) {
                    const int k1 = kk | bit;
                    float a0r = sr[kk], a0i = si[kk];
                    float a1r = sr[k1], a1i = si[k1];
                    sr[kk] = fmaf(cth, a0r,  sth * a1i);
                    si[kk] = fmaf(cth, a0i, -sth * a1r);
                    sr[k1] = fmaf(cth, a1r,  sth * a0i);
                    si[k1] = fmaf(cth, a1i, -sth * a0r);
                }
            }
        }
        #pragma unroll
        for (int q = 0; q < NQ; ++q) {
            const int bit = 8 >> q;
            float cth = pc[q], sth = ps[q];
            #pragma unroll
            for (int kk = 0; kk < DIMQ; ++kk) {
                if (!(kk & bit)) {
                    const int k1 = kk | bit;
                    float a0r = sr[kk], a0i = si[kk];
                    float a1r = sr[k1], a1i = si[k1];
                    sr[kk] = fmaf(cth, a0r,  sth * a1i);
                    si[kk] = fmaf(cth, a0i, -sth * a1r);
                    sr[k1] = fmaf(cth, a1r,  sth * a0i);
                    si[k1] = fmaf(cth, a1i, -sth * a0r);
                }
            }
            const int cbit = 8 >> q;
            const int tbit = 8 >> ((q + 1) & 3);
            #pragma unroll
            for (int kk = 0; kk < DIMQ; ++kk) {
                if ((kk & cbit) && !(kk & tbit)) {
                    const int k1 = kk | tbit;
                    float tswap;
                    tswap = sr[kk]; sr[kk] = sr[k1]; sr[k1] = tswap;
                    tswap = si[kk]; si[kk] = si[k1]; si[k1] = tswap;
                }
            }
        }

        float pr[DIMQ];
        #pragma unroll
        for (int kk = 0; kk < DIMQ; ++kk) pr[kk] = fmaf(sr[kk], sr[kk], si[kk] * si[kk]);

        float qv0 = 0.f, qv1 = 0.f, qv2 = 0.f, qv3 = 0.f;
        #pragma unroll
        for (int kk = 0; kk < DIMQ; ++kk) {
            qv0 += (kk & 8) ? -pr[kk] : pr[kk];
            qv1 += (kk & 4) ? -pr[kk] : pr[kk];
            qv2 += (kk & 2) ? -pr[kk] : pr[kk];
            qv3 += (kk & 1) ? -pr[kk] : pr[kk];
        }
        *(float4*)&s_q[tid * 4] = make_float4(qv0, qv1, qv2, qv3);
    }

    __syncthreads();

    // ---- output: thread owns 4 fixed columns, loops over 64 rows ----
    float4* out4 = (float4*)out;
    #pragma unroll 8
    for (int i = 0; i < TPB; ++i) {
        int grow = tile + i;
        if (grow < n_tokens) {
            float4 qq = *(const float4*)&s_q[i * 4];  // broadcast read
            float4 v;
            v.x = fmaf(qq.x, wo0.x, fmaf(qq.y, wo1.x, fmaf(qq.z, wo2.x, fmaf(qq.w, wo3.x, bo4.x))));
            v.y = fmaf(qq.x, wo0.y, fmaf(qq.y, wo1.y, fmaf(qq.z, wo2.y, fmaf(qq.w, wo3.y, bo4.y))));
            v.z = fmaf(qq.x, wo0.z, fmaf(qq.y, wo1.z, fmaf(qq.z, wo2.z, fmaf(qq.w, wo3.z, bo4.z))));
            v.w = fmaf(qq.x, wo0.w, fmaf(qq.y, wo1.w, fmaf(qq.z, wo2.w, fmaf(qq.w, wo3.w, bo4.w))));
            out4[(size_t)grow * 256 + tid] = v;
        }
    }
}

extern "C" void kernel_launch(void* const* d_in, const int* in_sizes, int n_in,
                              void* d_out, int out_size, void* d_ws, size_t ws_size,
                              hipStream_t stream)
{
    (void)d_ws; (void)ws_size; (void)n_in; (void)out_size;
    const float* x  = (const float*)d_in[0];
    const float* Wi = (const float*)d_in[1];
    const float* bi = (const float*)d_in[2];
    const float* Wo = (const float*)d_in[3];
    const float* bo = (const float*)d_in[4];
    const float* fp = (const float*)d_in[5];
    float* out = (float*)d_out;

    int n_tokens = in_sizes[0] / D_MODEL;
    int grid = (n_tokens + TPB - 1) / TPB;
    qffn_kernel<<<grid, 256, 0, stream>>>(x, Wi, bi, Wo, bo, fp, out, n_tokens);
}